// Round 4
// baseline (475.581 us; speedup 1.0000x reference)
//
#include <hip/hip_runtime.h>

// out[v, t, n] = tlut[encoded[t, n], v]
// tlut: (65536, 2) f32 row-major -> tlut[e*2 + v], i.e. one float2 per entry.
// encoded: (128, 262144) i32, flat i = t*N + n.
// out: (2, 128, 262144) f32, plane v at offset v * (TB*N).
//
// Memory-bound gather: 128 MB idx read + 256 MB out write + L2-cached 512 KB LUT.

__global__ __launch_bounds__(256) void bitshift_codebook_kernel(
    const float* __restrict__ tlut,
    const int*   __restrict__ encoded,
    float*       __restrict__ out,
    long long total)   // TB*N, number of encoded elements (multiple of 4)
{
    const long long total_vec = total >> 2;                    // int4 units
    const long long stride = (long long)gridDim.x * blockDim.x;
    float* __restrict__ out1 = out + total;                    // v=1 plane

    const int4*   __restrict__ enc4 = reinterpret_cast<const int4*>(encoded);
    const float2* __restrict__ lut2 = reinterpret_cast<const float2*>(tlut);
    float4* __restrict__ out0_4 = reinterpret_cast<float4*>(out);
    float4* __restrict__ out1_4 = reinterpret_cast<float4*>(out1);

    for (long long i = (long long)blockIdx.x * blockDim.x + threadIdx.x;
         i < total_vec; i += stride) {
        int4 e = enc4[i];
        float2 a = lut2[e.x];
        float2 b = lut2[e.y];
        float2 c = lut2[e.z];
        float2 d = lut2[e.w];
        float4 v0, v1;
        v0.x = a.x; v0.y = b.x; v0.z = c.x; v0.w = d.x;
        v1.x = a.y; v1.y = b.y; v1.z = c.y; v1.w = d.y;
        out0_4[i] = v0;
        out1_4[i] = v1;
    }
}

extern "C" void kernel_launch(void* const* d_in, const int* in_sizes, int n_in,
                              void* d_out, int out_size, void* d_ws, size_t ws_size,
                              hipStream_t stream) {
    const float* tlut    = (const float*)d_in[0];   // (65536, 2) f32
    const int*   encoded = (const int*)d_in[1];     // (128, 262144) i32
    float*       out     = (float*)d_out;           // (2, 128, 262144) f32

    const long long total = (long long)in_sizes[1]; // TB*N = 33,554,432
    const long long total_vec = total >> 2;

    const int block = 256;
    long long want = (total_vec + block - 1) / block;
    int grid = (int)(want < 2048 ? want : 2048);

    bitshift_codebook_kernel<<<grid, block, 0, stream>>>(tlut, encoded, out, total);
}